// Round 1
// baseline (128211.035 us; speedup 1.0000x reference)
//
#include <hip/hip_runtime.h>
#include <math.h>
#include <float.h>

// Problem constants (reference: B=256, H=1024, I=1, O=512, T=512)
#define NB 256
#define NH 1024
#define NO 512
#define NT 512

// Workspace layout (float offsets)
#define OFF_HT0   0                       // hT ping  [H][B]
#define OFF_HT1   (256*1024)              // hT pong  [H][B]
#define OFF_HPL   (2*256*1024)            // h plain  [B][H]
#define OFF_CT    (3*256*1024)            // cT       [H][B]
#define OFF_BIAS  (4*256*1024)            // b_ih+b_hh [4H]
#define OFF_WLT   (OFF_BIAS + 4096)       // w_lin^T  [H][O]
#define OFF_PART  (OFF_WLT + 1024*512)    // argmax partials [B][4][{val,idx}]

// ---------------------------------------------------------------------------
// Init: transpose w_lin, stage h0=z (both layouts), c=0, bias sum, argmax
// partials seeded to (-FLT_MAX, 0) so step 0 sees xin = 0.
// ---------------------------------------------------------------------------
__global__ void k_init(const float* __restrict__ z, const float* __restrict__ b_ih,
                       const float* __restrict__ b_hh, const float* __restrict__ w_lin,
                       float* __restrict__ ws) {
  int idx = blockIdx.x * 256 + threadIdx.x;
  if (idx < 1024 * 512) {                 // wlinT[u][o] = w_lin[o][u]
    int u = idx >> 9, o = idx & 511;
    ws[OFF_WLT + idx] = w_lin[o * 1024 + u];
  }
  if (idx < 256 * 1024) {                 // hT0[u][b] = z[b][u]; hplain = z; cT = 0
    int u = idx >> 8, b = idx & 255;
    ws[OFF_HT0 + idx] = z[b * 1024 + u];
    ws[OFF_HPL + idx] = z[idx];
    ws[OFF_CT + idx] = 0.f;
  }
  if (idx < 4096) ws[OFF_BIAS + idx] = b_ih[idx] + b_hh[idx];
  if (idx < 2048) ws[OFF_PART + idx] = (idx & 1) ? 0.f : -FLT_MAX;
}

// ---------------------------------------------------------------------------
// K1: gates = h @ w_hh^T (+ bias + xin*w_ih) fused with LSTM cell update.
// 256 blocks x 256 threads. thread <-> batch b; block <-> 4 hidden units u
// (16 gate rows j = g*1024 + u0+uu). Weight addresses are wave-uniform so the
// compiler streams them through s_load/SGPRs; h comes from hT[k][b]
// (coalesced). h is double-buffered across steps (hTin/hTout).
// ---------------------------------------------------------------------------
__global__ __launch_bounds__(256, 1) void k_gates(
    const float* __restrict__ w_hh, const float* __restrict__ w_ih,
    const float* __restrict__ hTin, float* __restrict__ hTout,
    float* __restrict__ ws) {
  const int b = threadIdx.x;
  const int u0 = blockIdx.x << 2;
  const float* __restrict__ wbase = w_hh + (u0 << 10);

  float acc[16];
#pragma unroll
  for (int a = 0; a < 16; ++a) acc[a] = 0.f;

  // Software-pipelined h loads (latency ~200cy L2-hit) over 8-k chunks.
  float ha[8], hb2[8];
#pragma unroll
  for (int kk = 0; kk < 8; ++kk) ha[kk] = hTin[kk * 256 + b];

  for (int kc = 0; kc < 1024; kc += 16) {
#pragma unroll
    for (int kk = 0; kk < 8; ++kk) hb2[kk] = hTin[(kc + 8 + kk) * 256 + b];
#pragma unroll
    for (int kk = 0; kk < 8; ++kk) {
      const float hv = ha[kk];
      const int k = kc + kk;
#pragma unroll
      for (int g = 0; g < 4; ++g)
#pragma unroll
        for (int uu = 0; uu < 4; ++uu)
          acc[g * 4 + uu] = fmaf(wbase[(g << 20) + (uu << 10) + k], hv, acc[g * 4 + uu]);
    }
    if (kc + 16 < 1024) {
#pragma unroll
      for (int kk = 0; kk < 8; ++kk) ha[kk] = hTin[(kc + 16 + kk) * 256 + b];
    }
#pragma unroll
    for (int kk = 0; kk < 8; ++kk) {
      const float hv = hb2[kk];
      const int k = kc + 8 + kk;
#pragma unroll
      for (int g = 0; g < 4; ++g)
#pragma unroll
        for (int uu = 0; uu < 4; ++uu)
          acc[g * 4 + uu] = fmaf(wbase[(g << 20) + (uu << 10) + k], hv, acc[g * 4 + uu]);
    }
  }

  // xin[b] = argmax of previous step's head (4 o-quarter partials, first-index
  // tiebreak via strict >, partials stored in ascending o order).
  const float* __restrict__ part = ws + OFF_PART;
  float4 p01 = *(const float4*)(part + b * 8);
  float4 p23 = *(const float4*)(part + b * 8 + 4);
  float v = p01.x, ix = p01.y;
  if (p01.z > v) { v = p01.z; ix = p01.w; }
  if (p23.x > v) { v = p23.x; ix = p23.y; }
  if (p23.z > v) { v = p23.z; ix = p23.w; }
  const float xb = ix;

  const float* __restrict__ bias = ws + OFF_BIAS;
  float* __restrict__ cT = ws + OFF_CT;
  float4 hout;
  float* hp = &hout.x;
#pragma unroll
  for (int uu = 0; uu < 4; ++uu) {
    const int u = u0 + uu;
    float gi = acc[0 + uu]  + bias[u]        + xb * w_ih[u];
    float gf = acc[4 + uu]  + bias[1024 + u] + xb * w_ih[1024 + u];
    float gg = acc[8 + uu]  + bias[2048 + u] + xb * w_ih[2048 + u];
    float go = acc[12 + uu] + bias[3072 + u] + xb * w_ih[3072 + u];
    float co = cT[u * 256 + b];
    // accurate expf/tanhf (NOT __expf: argmax feedback needs ~1e-6 accuracy)
    float cn = (1.f / (1.f + expf(-gf))) * co + (1.f / (1.f + expf(-gi))) * tanhf(gg);
    float hn = (1.f / (1.f + expf(-go))) * tanhf(cn);
    cT[u * 256 + b] = cn;
    hTout[u * 256 + b] = hn;
    hp[uu] = hn;
  }
  float* __restrict__ hpl = ws + OFF_HPL;
  *(float4*)(hpl + b * 1024 + u0) = hout;   // row-major copy for the head kernel
}

// ---------------------------------------------------------------------------
// K2: head x_t = h @ w_lin^T + b_lin, write out[b][t][:], per-block argmax
// partial over a 128-o quarter for 4 batch rows. 256 blocks x 128 threads:
// block = (b-quad, o-quarter); thread <-> one o.
// ---------------------------------------------------------------------------
__global__ __launch_bounds__(128, 2) void k_head(
    const float* __restrict__ b_lin, float* __restrict__ out,
    float* __restrict__ ws, int t) {
  const int tid = threadIdx.x;
  const int oq = blockIdx.x & 3;
  const int b0 = (blockIdx.x >> 2) << 2;
  const int o = (oq << 7) + tid;
  const float* __restrict__ hpl = ws + OFF_HPL;
  const float* __restrict__ wlt = ws + OFF_WLT;

  __shared__ float sh[4][1024];
  __shared__ float rv[4][128];
  __shared__ float ri[4][128];
#pragma unroll
  for (int i = 0; i < 4; ++i) {
    float4 v0 = *(const float4*)(hpl + (b0 + i) * 1024 + tid * 8);
    float4 v1 = *(const float4*)(hpl + (b0 + i) * 1024 + tid * 8 + 4);
    *(float4*)(&sh[i][tid * 8]) = v0;
    *(float4*)(&sh[i][tid * 8 + 4]) = v1;
  }
  __syncthreads();

  float a0 = 0.f, a1 = 0.f, a2 = 0.f, a3 = 0.f;
  for (int u = 0; u < 1024; u += 4) {
    float w0 = wlt[(u + 0) * 512 + o];
    float w1 = wlt[(u + 1) * 512 + o];
    float w2 = wlt[(u + 2) * 512 + o];
    float w3 = wlt[(u + 3) * 512 + o];
    float4 h0 = *(const float4*)(&sh[0][u]);
    float4 h1 = *(const float4*)(&sh[1][u]);
    float4 h2 = *(const float4*)(&sh[2][u]);
    float4 h3 = *(const float4*)(&sh[3][u]);
    a0 = fmaf(h0.w, w3, fmaf(h0.z, w2, fmaf(h0.y, w1, fmaf(h0.x, w0, a0))));
    a1 = fmaf(h1.w, w3, fmaf(h1.z, w2, fmaf(h1.y, w1, fmaf(h1.x, w0, a1))));
    a2 = fmaf(h2.w, w3, fmaf(h2.z, w2, fmaf(h2.y, w1, fmaf(h2.x, w0, a2))));
    a3 = fmaf(h3.w, w3, fmaf(h3.z, w2, fmaf(h3.y, w1, fmaf(h3.x, w0, a3))));
  }
  const float bl = b_lin[o];
  a0 += bl; a1 += bl; a2 += bl; a3 += bl;

  const int obase = t * 512 + o;
  out[(b0 + 0) * (NT * NO) + obase] = a0;
  out[(b0 + 1) * (NT * NO) + obase] = a1;
  out[(b0 + 2) * (NT * NO) + obase] = a2;
  out[(b0 + 3) * (NT * NO) + obase] = a3;

  rv[0][tid] = a0; ri[0][tid] = (float)o;
  rv[1][tid] = a1; ri[1][tid] = (float)o;
  rv[2][tid] = a2; ri[2][tid] = (float)o;
  rv[3][tid] = a3; ri[3][tid] = (float)o;
  __syncthreads();
  for (int s = 64; s > 0; s >>= 1) {
    if (tid < s) {
#pragma unroll
      for (int i = 0; i < 4; ++i) {
        if (rv[i][tid + s] > rv[i][tid]) {   // strict >: first index wins ties
          rv[i][tid] = rv[i][tid + s];
          ri[i][tid] = ri[i][tid + s];
        }
      }
    }
    __syncthreads();
  }
  if (tid < 4) {
    float* __restrict__ part = ws + OFF_PART;
    part[(b0 + tid) * 8 + oq * 2 + 0] = rv[tid][0];
    part[(b0 + tid) * 8 + oq * 2 + 1] = ri[tid][0];
  }
}

extern "C" void kernel_launch(void* const* d_in, const int* in_sizes, int n_in,
                              void* d_out, int out_size, void* d_ws, size_t ws_size,
                              hipStream_t stream) {
  const float* z     = (const float*)d_in[0];
  const float* w_ih  = (const float*)d_in[1];
  const float* w_hh  = (const float*)d_in[2];
  const float* b_ih  = (const float*)d_in[3];
  const float* b_hh  = (const float*)d_in[4];
  const float* w_lin = (const float*)d_in[5];
  const float* b_lin = (const float*)d_in[6];
  float* out = (float*)d_out;
  float* ws  = (float*)d_ws;

  k_init<<<2048, 256, 0, stream>>>(z, b_ih, b_hh, w_lin, ws);
  for (int t = 0; t < NT; ++t) {
    const float* hTin = ws + ((t & 1) ? OFF_HT1 : OFF_HT0);
    float* hTout      = ws + ((t & 1) ? OFF_HT0 : OFF_HT1);
    k_gates<<<256, 256, 0, stream>>>(w_hh, w_ih, hTin, hTout, ws);
    k_head<<<256, 128, 0, stream>>>(b_lin, out, ws, t);
  }
}

// Round 2
// 47418.042 us; speedup vs baseline: 2.7038x; 2.7038x over previous
//
#include <hip/hip_runtime.h>
#include <math.h>
#include <float.h>

// Problem constants (reference: B=256, H=1024, I=1, O=512, T=512)
#define NB 256
#define NH 1024
#define NO 512
#define NT 512

// Workspace layout (float offsets)
// hT4 layout: [q=u>>2][b][j=u&3]  -> index q*1024 + b*4 + j  (256K floats)
#define OFF_HT4_0 0
#define OFF_HT4_1 (256*1024)
#define OFF_CT    (2*256*1024)            // cT [u][b]
#define OFF_BIAS  (3*256*1024)            // b_ih+b_hh [4H]
#define OFF_WLT   (OFF_BIAS + 4096)       // w_lin^T [H][O]
#define OFF_PART  (OFF_WLT + 1024*512)    // argmax partials [B][4][{val,idx}]

__device__ __forceinline__ float sigf(float x) { return 1.f / (1.f + expf(-x)); }

// ---------------------------------------------------------------------------
// Init: pack h0=z into hT4 ping, c=0, bias sum, w_lin transpose, argmax
// partials seeded to (-FLT_MAX, 0) so step 0 sees xin = 0.
// ---------------------------------------------------------------------------
__global__ void k_init(const float* __restrict__ z, const float* __restrict__ b_ih,
                       const float* __restrict__ b_hh, const float* __restrict__ w_lin,
                       float* __restrict__ ws) {
  int idx = blockIdx.x * 256 + threadIdx.x;
  if (idx < 1024 * 512) {                 // wlinT[u][o] = w_lin[o][u]
    int u = idx >> 9, o = idx & 511;
    ws[OFF_WLT + idx] = w_lin[o * 1024 + u];
  }
  if (idx < 256 * 1024) {                 // hT4[q][b][j] = z[b][q*4+j]; cT = 0
    int q = idx >> 10, r = idx & 1023;
    int b = r >> 2, j = r & 3;
    ws[OFF_HT4_0 + idx] = z[b * 1024 + (q << 2) + j];
    ws[OFF_CT + idx] = 0.f;
  }
  if (idx < 4096) ws[OFF_BIAS + idx] = b_ih[idx] + b_hh[idx];
  if (idx < 2048) ws[OFF_PART + idx] = (idx & 1) ? 0.f : -FLT_MAX;
}

#define FMA4(A, W, H) \
  A = fmaf((W).x, (H).x, A); A = fmaf((W).y, (H).y, A); \
  A = fmaf((W).z, (H).z, A); A = fmaf((W).w, (H).w, A);

// ---------------------------------------------------------------------------
// K1: gates = h @ w_hh^T (+ bias + xin*w_ih) fused with LSTM cell update.
// 256 blocks x 256 threads. Block owns units u0..u0+3 (16 gate rows).
// Wave uu owns unit u0+uu (its 4 gate rows i,f,g,o -> cell update is
// thread-local). Lane l owns b in {l, l+64, l+128, l+192} (NBT=4: one
// weight value feeds 4 FMAs). Weights staged to LDS (64KB) once per step;
// inner loop: 4 ds_read_b128 (broadcast) + 4 global dwordx4 (h) + 64 FMA
// per 4-k group. h double-buffered across steps in hT4 packed layout.
// ---------------------------------------------------------------------------
__global__ __launch_bounds__(256, 1) void k_gates(
    const float* __restrict__ w_hh, const float* __restrict__ w_ih,
    const float* __restrict__ hT4in, float* __restrict__ hT4out,
    float* __restrict__ ws) {
  __shared__ float wlds[16 * 1024];       // [r = uu*4+g][k], 64 KB
  const int tid = threadIdx.x;
  const int u0 = blockIdx.x << 2;
  const int lane = tid & 63;
  const int uu = tid >> 6;

  // Stage 16 weight rows, fully coalesced (row r, float4 tid per iteration).
#pragma unroll
  for (int r = 0; r < 16; ++r) {
    int ru = r >> 2, g = r & 3;           // global row g*1024 + u0 + ru
    const float4 v = *(const float4*)(w_hh + ((g * 1024 + u0 + ru) << 10) + (tid << 2));
    *(float4*)(&wlds[(r << 10) + (tid << 2)]) = v;
  }
  __syncthreads();

  const float* __restrict__ wrow = &wlds[(uu << 2) << 10];  // rows g=0..3 of unit u0+uu
  const float* __restrict__ hbase = hT4in + (lane << 2);    // + bb*256 + q*1024

  float acc[4][4];                        // [gate][bb]
#pragma unroll
  for (int g = 0; g < 4; ++g)
#pragma unroll
    for (int bb = 0; bb < 4; ++bb) acc[g][bb] = 0.f;

  float4 hA[4], hB[4];
#pragma unroll
  for (int bb = 0; bb < 4; ++bb) hA[bb] = *(const float4*)(hbase + (bb << 8));

  for (int q = 0; q < 256; q += 2) {
    // prefetch q+1
#pragma unroll
    for (int bb = 0; bb < 4; ++bb)
      hB[bb] = *(const float4*)(hbase + ((q + 1) << 10) + (bb << 8));
    {
      const float4 w0 = *(const float4*)(&wrow[(0 << 10) + (q << 2)]);
      const float4 w1 = *(const float4*)(&wrow[(1 << 10) + (q << 2)]);
      const float4 w2 = *(const float4*)(&wrow[(2 << 10) + (q << 2)]);
      const float4 w3 = *(const float4*)(&wrow[(3 << 10) + (q << 2)]);
#pragma unroll
      for (int bb = 0; bb < 4; ++bb) {
        const float4 h = hA[bb];
        FMA4(acc[0][bb], w0, h); FMA4(acc[1][bb], w1, h);
        FMA4(acc[2][bb], w2, h); FMA4(acc[3][bb], w3, h);
      }
    }
    // prefetch q+2
    if (q + 2 < 256) {
#pragma unroll
      for (int bb = 0; bb < 4; ++bb)
        hA[bb] = *(const float4*)(hbase + ((q + 2) << 10) + (bb << 8));
    }
    {
      const int q1 = q + 1;
      const float4 w0 = *(const float4*)(&wrow[(0 << 10) + (q1 << 2)]);
      const float4 w1 = *(const float4*)(&wrow[(1 << 10) + (q1 << 2)]);
      const float4 w2 = *(const float4*)(&wrow[(2 << 10) + (q1 << 2)]);
      const float4 w3 = *(const float4*)(&wrow[(3 << 10) + (q1 << 2)]);
#pragma unroll
      for (int bb = 0; bb < 4; ++bb) {
        const float4 h = hB[bb];
        FMA4(acc[0][bb], w0, h); FMA4(acc[1][bb], w1, h);
        FMA4(acc[2][bb], w2, h); FMA4(acc[3][bb], w3, h);
      }
    }
  }

  // Epilogue: thread-local cell update for unit u = u0+uu, 4 batch columns.
  const int u = u0 + uu;
  const float* __restrict__ bias = ws + OFF_BIAS;
  const float* __restrict__ part = ws + OFF_PART;
  float* __restrict__ cT = ws + OFF_CT;
  // wave-uniform operands
  const float bi = bias[u],        bf = bias[1024 + u];
  const float bg = bias[2048 + u], bo = bias[3072 + u];
  const float wi = w_ih[u],        wf = w_ih[1024 + u];
  const float wg = w_ih[2048 + u], wo = w_ih[3072 + u];

#pragma unroll
  for (int bb = 0; bb < 4; ++bb) {
    const int b = lane + (bb << 6);
    // xin[b]: combine 4 o-quarter argmax partials (ascending o; strict > =>
    // first index wins ties)
    const float4 p01 = *(const float4*)(part + b * 8);
    const float4 p23 = *(const float4*)(part + b * 8 + 4);
    float v = p01.x, ix = p01.y;
    if (p01.z > v) { v = p01.z; ix = p01.w; }
    if (p23.x > v) { v = p23.x; ix = p23.y; }
    if (p23.z > v) { v = p23.z; ix = p23.w; }
    const float xb = ix;

    const float gi = acc[0][bb] + bi + xb * wi;
    const float gf = acc[1][bb] + bf + xb * wf;
    const float gg = acc[2][bb] + bg + xb * wg;
    const float go = acc[3][bb] + bo + xb * wo;
    const float co = cT[(u << 8) + b];
    // accurate expf/tanhf (NOT __expf: argmax feedback needs ~1e-6 accuracy)
    const float cn = sigf(gf) * co + sigf(gi) * tanhf(gg);
    const float hn = sigf(go) * tanhf(cn);
    cT[(u << 8) + b] = cn;
    hT4out[((u0 >> 2) << 10) + (b << 2) + uu] = hn;
  }
}

// ---------------------------------------------------------------------------
// K2: head x_t = h @ w_lin^T + b_lin, write out[b][t][:], per-block argmax
// partial over a 128-o quarter for 4 batch rows. 256 blocks x 128 threads:
// block = (b-quad, o-quarter); thread <-> one o. h read from packed hT4.
// ---------------------------------------------------------------------------
__global__ __launch_bounds__(128, 2) void k_head(
    const float* __restrict__ b_lin, float* __restrict__ out,
    float* __restrict__ ws, int t, const float* __restrict__ hT4) {
  const int tid = threadIdx.x;
  const int oq = blockIdx.x & 3;
  const int b0 = (blockIdx.x >> 2) << 2;
  const int o = (oq << 7) + tid;
  const float* __restrict__ wlt = ws + OFF_WLT;

  __shared__ float sh[4][1024];
  __shared__ float rv[4][128];
  __shared__ float ri[4][128];
  // Stage h rows b0..b0+3 from hT4: idx -> (q, bb); 4-lane groups form 64B
  // contiguous segments.
#pragma unroll
  for (int i = 0; i < 8; ++i) {
    int idx = i * 128 + tid;              // [0,1024)
    int q = idx >> 2, bb = idx & 3;
    float4 v = *(const float4*)(hT4 + (q << 10) + ((b0 + bb) << 2));
    *(float4*)(&sh[bb][q << 2]) = v;
  }
  __syncthreads();

  float a0 = 0.f, a1 = 0.f, a2 = 0.f, a3 = 0.f;
  for (int u = 0; u < 1024; u += 4) {
    float w0 = wlt[(u + 0) * 512 + o];
    float w1 = wlt[(u + 1) * 512 + o];
    float w2 = wlt[(u + 2) * 512 + o];
    float w3 = wlt[(u + 3) * 512 + o];
    float4 h0 = *(const float4*)(&sh[0][u]);
    float4 h1 = *(const float4*)(&sh[1][u]);
    float4 h2 = *(const float4*)(&sh[2][u]);
    float4 h3 = *(const float4*)(&sh[3][u]);
    a0 = fmaf(h0.w, w3, fmaf(h0.z, w2, fmaf(h0.y, w1, fmaf(h0.x, w0, a0))));
    a1 = fmaf(h1.w, w3, fmaf(h1.z, w2, fmaf(h1.y, w1, fmaf(h1.x, w0, a1))));
    a2 = fmaf(h2.w, w3, fmaf(h2.z, w2, fmaf(h2.y, w1, fmaf(h2.x, w0, a2))));
    a3 = fmaf(h3.w, w3, fmaf(h3.z, w2, fmaf(h3.y, w1, fmaf(h3.x, w0, a3))));
  }
  const float bl = b_lin[o];
  a0 += bl; a1 += bl; a2 += bl; a3 += bl;

  const int obase = t * 512 + o;
  out[(b0 + 0) * (NT * NO) + obase] = a0;
  out[(b0 + 1) * (NT * NO) + obase] = a1;
  out[(b0 + 2) * (NT * NO) + obase] = a2;
  out[(b0 + 3) * (NT * NO) + obase] = a3;

  rv[0][tid] = a0; ri[0][tid] = (float)o;
  rv[1][tid] = a1; ri[1][tid] = (float)o;
  rv[2][tid] = a2; ri[2][tid] = (float)o;
  rv[3][tid] = a3; ri[3][tid] = (float)o;
  __syncthreads();
  for (int s = 64; s > 0; s >>= 1) {
    if (tid < s) {
#pragma unroll
      for (int i = 0; i < 4; ++i) {
        if (rv[i][tid + s] > rv[i][tid]) {   // strict >: first index wins ties
          rv[i][tid] = rv[i][tid + s];
          ri[i][tid] = ri[i][tid + s];
        }
      }
    }
    __syncthreads();
  }
  if (tid < 4) {
    float* __restrict__ part = ws + OFF_PART;
    part[(b0 + tid) * 8 + oq * 2 + 0] = rv[tid][0];
    part[(b0 + tid) * 8 + oq * 2 + 1] = ri[tid][0];
  }
}

extern "C" void kernel_launch(void* const* d_in, const int* in_sizes, int n_in,
                              void* d_out, int out_size, void* d_ws, size_t ws_size,
                              hipStream_t stream) {
  const float* z     = (const float*)d_in[0];
  const float* w_ih  = (const float*)d_in[1];
  const float* w_hh  = (const float*)d_in[2];
  const float* b_ih  = (const float*)d_in[3];
  const float* b_hh  = (const float*)d_in[4];
  const float* w_lin = (const float*)d_in[5];
  const float* b_lin = (const float*)d_in[6];
  float* out = (float*)d_out;
  float* ws  = (float*)d_ws;

  k_init<<<2048, 256, 0, stream>>>(z, b_ih, b_hh, w_lin, ws);
  for (int t = 0; t < NT; ++t) {
    const float* hin = ws + ((t & 1) ? OFF_HT4_1 : OFF_HT4_0);
    float* hout      = ws + ((t & 1) ? OFF_HT4_0 : OFF_HT4_1);
    k_gates<<<256, 256, 0, stream>>>(w_hh, w_ih, hin, hout, ws);
    k_head<<<256, 128, 0, stream>>>(b_lin, out, ws, t, hout);
  }
}